// Round 3
// baseline (7113.232 us; speedup 1.0000x reference)
//
#include <hip/hip_runtime.h>
#include <hip/hip_fp16.h>
#include <math.h>

#define N_NODES 100000
#define N_EDGES 3200000
#define F_INDIM 512
#define C_DIM 64
#define K_ITERS 50
#define ALPHA_F 0.1f

#define NCHUNK 4
#define CCH 16                       // channels per chunk
#define SLICE ((size_t)N_NODES * CCH)  // halfs per chunk slice (3.2 MB)

// ---------------------------------------------------------------------------
// CSR build
// ---------------------------------------------------------------------------
__global__ void init_deg_kernel(int* __restrict__ deg, int* __restrict__ cursor) {
    int i = blockIdx.x * 256 + threadIdx.x;
    if (i < N_NODES) { deg[i] = 1; cursor[i] = 0; }  // 1 = self loop
}

__global__ void count_deg_kernel(const int* __restrict__ dst, int* __restrict__ deg) {
    int e = blockIdx.x * 256 + threadIdx.x;
    if (e < N_EDGES) atomicAdd(&deg[dst[e]], 1);
}

__global__ void dinv_kernel(const int* __restrict__ deg, float* __restrict__ dinv) {
    int i = blockIdx.x * 256 + threadIdx.x;
    if (i < N_NODES) dinv[i] = rsqrtf((float)deg[i]);
}

__global__ void scan_block_kernel(const int* __restrict__ deg, int* __restrict__ row_ptr,
                                  int* __restrict__ blksum) {
    __shared__ int tmp[256];
    int i = blockIdx.x * 256 + threadIdx.x;
    int v = (i < N_NODES) ? deg[i] : 0;
    tmp[threadIdx.x] = v;
    __syncthreads();
    for (int o = 1; o < 256; o <<= 1) {
        int t = (threadIdx.x >= o) ? tmp[threadIdx.x - o] : 0;
        __syncthreads();
        tmp[threadIdx.x] += t;
        __syncthreads();
    }
    if (i < N_NODES) row_ptr[i] = tmp[threadIdx.x] - v;
    if (threadIdx.x == 255) blksum[blockIdx.x] = tmp[255];
}

__global__ void scan_top_kernel(int* __restrict__ blksum, int nb) {
    __shared__ int tmp[512];
    int v = (threadIdx.x < nb) ? blksum[threadIdx.x] : 0;
    tmp[threadIdx.x] = v;
    __syncthreads();
    for (int o = 1; o < 512; o <<= 1) {
        int t = (threadIdx.x >= o) ? tmp[threadIdx.x - o] : 0;
        __syncthreads();
        tmp[threadIdx.x] += t;
        __syncthreads();
    }
    if (threadIdx.x < nb) blksum[threadIdx.x] = tmp[threadIdx.x] - v;
}

__global__ void scan_add_kernel(int* __restrict__ row_ptr, const int* __restrict__ blksum) {
    int i = blockIdx.x * 256 + threadIdx.x;
    if (i < N_NODES) row_ptr[i] += blksum[blockIdx.x];
    if (i == 0) row_ptr[N_NODES] = N_EDGES + N_NODES;
}

// packed edge: (col << 15) | (fp16 bits of val, sign always 0 -> 15 bits)
__global__ void scatter_kernel(const int* __restrict__ src, const int* __restrict__ dst,
                               const float* __restrict__ dinv, const int* __restrict__ row_ptr,
                               int* __restrict__ cursor, unsigned int* __restrict__ pairs) {
    int e = blockIdx.x * 256 + threadIdx.x;
    if (e < N_EDGES) {
        int s = src[e], d = dst[e];
        int pos = atomicAdd(&cursor[d], 1);
        unsigned short hv = __half_as_ushort(__float2half(dinv[s] * dinv[d]));
        pairs[row_ptr[d] + pos] = ((unsigned int)s << 15) | (unsigned int)(hv & 0x7FFF);
    } else if (e < N_EDGES + N_NODES) {
        int i = e - N_EDGES;
        int pos = atomicAdd(&cursor[i], 1);
        float di = dinv[i];
        unsigned short hv = __half_as_ushort(__float2half(di * di));
        pairs[row_ptr[i] + pos] = ((unsigned int)i << 15) | (unsigned int)(hv & 0x7FFF);
    }
}

// ---------------------------------------------------------------------------
// GEMM: h0 = relu(x @ W + b) -> h0h in chunked fp16 layout [4][N][16]
// 128 rows x 64 cols per block, 256 threads, 4x8 register blocking.
// ---------------------------------------------------------------------------
__global__ __launch_bounds__(256) void gemm_relu_kernel(const float* __restrict__ x,
                                                        const float* __restrict__ W,
                                                        const float* __restrict__ b,
                                                        __half* __restrict__ h0h) {
    __shared__ float xs[128][36];
    __shared__ float ws[32][64];
    const int tid = threadIdx.x;
    const int c0 = (tid & 7) * 8;        // 8 output cols
    const int r0 = (tid >> 3) * 4;       // 4 output rows
    const int row0 = blockIdx.x * 128;

    float acc[4][8];
#pragma unroll
    for (int j = 0; j < 4; j++)
#pragma unroll
        for (int i = 0; i < 8; i++) acc[j][i] = 0.f;

    for (int kc = 0; kc < 16; kc++) {
        const int k0 = kc * 32;
        __syncthreads();
#pragma unroll
        for (int p = 0; p < 4; p++) {
            int lr = p * 32 + (tid >> 3);
            int gr = row0 + lr;
            if (gr >= N_NODES) gr = N_NODES - 1;
            float4 v = *reinterpret_cast<const float4*>(
                &x[(size_t)gr * F_INDIM + k0 + (tid & 7) * 4]);
            *reinterpret_cast<float4*>(&xs[lr][(tid & 7) * 4]) = v;
        }
#pragma unroll
        for (int p = 0; p < 2; p++) {
            int fi = p * 256 + tid;
            float4 v = *reinterpret_cast<const float4*>(
                &W[(size_t)(k0 + (fi >> 4)) * C_DIM + (fi & 15) * 4]);
            *reinterpret_cast<float4*>(&ws[fi >> 4][(fi & 15) * 4]) = v;
        }
        __syncthreads();
#pragma unroll
        for (int k = 0; k < 32; k++) {
            float4 w0 = *reinterpret_cast<const float4*>(&ws[k][c0]);
            float4 w1 = *reinterpret_cast<const float4*>(&ws[k][c0 + 4]);
            float wr[8] = {w0.x, w0.y, w0.z, w0.w, w1.x, w1.y, w1.z, w1.w};
#pragma unroll
            for (int j = 0; j < 4; j++) {
                float xv = xs[r0 + j][k];
#pragma unroll
                for (int i = 0; i < 8; i++) acc[j][i] = fmaf(xv, wr[i], acc[j][i]);
            }
        }
    }

    const float4 b0 = *reinterpret_cast<const float4*>(&b[c0]);
    const float4 b1 = *reinterpret_cast<const float4*>(&b[c0 + 4]);
    float bb[8] = {b0.x, b0.y, b0.z, b0.w, b1.x, b1.y, b1.z, b1.w};
    const int chunk = c0 >> 4;
    const int coff = c0 & 15;
#pragma unroll
    for (int j = 0; j < 4; j++) {
        int gr = row0 + r0 + j;
        if (gr < N_NODES) {
            float o[8];
#pragma unroll
            for (int i = 0; i < 8; i++) {
                float v = acc[j][i] + bb[i];
                o[i] = v > 0.f ? v : 0.f;
            }
            union { float4 f; __half2 h[4]; } hw;
            hw.h[0] = __floats2half2_rn(o[0], o[1]);
            hw.h[1] = __floats2half2_rn(o[2], o[3]);
            hw.h[2] = __floats2half2_rn(o[4], o[5]);
            hw.h[3] = __floats2half2_rn(o[6], o[7]);
            *reinterpret_cast<float4*>(h0h + (size_t)chunk * SLICE + (size_t)gr * CCH + coff) = hw.f;
        }
    }
}

// ---------------------------------------------------------------------------
// One propagation step over one channel chunk:
//   hn[chunk] = 0.9 * (A_hat @ hp[chunk]) + 0.1 * x0[chunk]
// Grid is chunk-major: all XCDs work the same 3.2 MB slice -> L2-resident.
// Wave: 2 lanes/edge (cp=lane&1 -> 8 ch each), 32 edges in flight (esub).
// ---------------------------------------------------------------------------
__device__ __forceinline__ void acc_fma8(float acc[8], float v, float4 g) {
    union { float f; __half2 h; } u;
    u.f = g.x; float2 f0 = __half22float2(u.h);
    acc[0] = fmaf(v, f0.x, acc[0]); acc[1] = fmaf(v, f0.y, acc[1]);
    u.f = g.y; float2 f1 = __half22float2(u.h);
    acc[2] = fmaf(v, f1.x, acc[2]); acc[3] = fmaf(v, f1.y, acc[3]);
    u.f = g.z; float2 f2 = __half22float2(u.h);
    acc[4] = fmaf(v, f2.x, acc[4]); acc[5] = fmaf(v, f2.y, acc[5]);
    u.f = g.w; float2 f3 = __half22float2(u.h);
    acc[6] = fmaf(v, f3.x, acc[6]); acc[7] = fmaf(v, f3.y, acc[7]);
}

#define BPC 25000  // blocks per chunk = N_NODES / 4

__global__ __launch_bounds__(256) void spmm_step_kernel(const int* __restrict__ rp,
                                                        const unsigned int* __restrict__ pairs,
                                                        const __half* __restrict__ hp,
                                                        const __half* __restrict__ x0,
                                                        __half* __restrict__ hn) {
    const int chunk = blockIdx.x / BPC;
    const int nb = blockIdx.x % BPC;
    const int node = nb * 4 + (threadIdx.x >> 6);
    if (node >= N_NODES) return;
    const int lane = threadIdx.x & 63;
    const int esub = lane >> 1;      // 0..31: edge slot
    const int cp = lane & 1;         // 0/1: which 8-channel half

    const __half* __restrict__ hps = hp + (size_t)chunk * SLICE;

    const int s = rp[node];
    const int e = rp[node + 1];

    float acc[8] = {0.f, 0.f, 0.f, 0.f, 0.f, 0.f, 0.f, 0.f};

    int j0 = s + esub;
    unsigned int pA = 0, pB = 0;   // col 0 / val +0 when inactive
    if (j0 < e) pA = __builtin_nontemporal_load(pairs + j0);
    if (j0 + 32 < e) pB = __builtin_nontemporal_load(pairs + j0 + 32);

    for (int t = s; t < e; t += 64) {
        unsigned int nA = 0, nB = 0;
        int jn = t + 64 + esub;
        if (jn < e) nA = __builtin_nontemporal_load(pairs + jn);
        if (jn + 32 < e) nB = __builtin_nontemporal_load(pairs + jn + 32);
        {
            int col = (int)(pA >> 15);
            float v = __half2float(__ushort_as_half((unsigned short)(pA & 0x7FFFu)));
            float4 g = *reinterpret_cast<const float4*>(hps + (size_t)col * CCH + cp * 8);
            acc_fma8(acc, v, g);
        }
        {
            int col = (int)(pB >> 15);
            float v = __half2float(__ushort_as_half((unsigned short)(pB & 0x7FFFu)));
            float4 g = *reinterpret_cast<const float4*>(hps + (size_t)col * CCH + cp * 8);
            acc_fma8(acc, v, g);
        }
        pA = nA; pB = nB;
    }

    // halving butterfly reduction over esub (5 bits); track channel base cb
    int cb = cp * 8;
    {   // xor 2: 8 -> 4
        const bool hi = (esub & 1);
#pragma unroll
        for (int i = 0; i < 4; i++) {
            float send = hi ? acc[i] : acc[i + 4];
            float keep = hi ? acc[i + 4] : acc[i];
            acc[i] = keep + __shfl_xor(send, 2);
        }
        if (hi) cb += 4;
    }
    {   // xor 4: 4 -> 2
        const bool hi = (esub & 2);
#pragma unroll
        for (int i = 0; i < 2; i++) {
            float send = hi ? acc[i] : acc[i + 2];
            float keep = hi ? acc[i + 2] : acc[i];
            acc[i] = keep + __shfl_xor(send, 4);
        }
        if (hi) cb += 2;
    }
    {   // xor 8: 2 -> 1
        const bool hi = (esub & 4);
        float send = hi ? acc[0] : acc[1];
        float keep = hi ? acc[1] : acc[0];
        acc[0] = keep + __shfl_xor(send, 8);
        if (hi) cb += 1;
    }
    acc[0] += __shfl_xor(acc[0], 16);
    acc[0] += __shfl_xor(acc[0], 32);

    if (esub < 8) {   // 16 lanes hold the 16 distinct channels
        size_t idx = (size_t)chunk * SLICE + (size_t)node * CCH + cb;
        float xv = __half2float(__ushort_as_half(
            __builtin_nontemporal_load((const unsigned short*)(x0 + idx))));
        float o = (1.0f - ALPHA_F) * acc[0] + ALPHA_F * xv;
        __builtin_nontemporal_store(__half_as_ushort(__float2half(o)),
                                    (unsigned short*)(hn + idx));
    }
}

// ---------------------------------------------------------------------------
// log_softmax over 64 channels (one wave per node), chunked fp16 in -> fp32 out
// ---------------------------------------------------------------------------
__global__ __launch_bounds__(256) void logsoftmax_kernel(const __half* __restrict__ h,
                                                         float* __restrict__ out) {
    int node = blockIdx.x * 4 + (threadIdx.x >> 6);
    if (node >= N_NODES) return;
    int c = threadIdx.x & 63;
    float v = __half2float(h[(size_t)(c >> 4) * SLICE + (size_t)node * CCH + (c & 15)]);
    float m = v;
#pragma unroll
    for (int o = 32; o > 0; o >>= 1) m = fmaxf(m, __shfl_xor(m, o));
    float ex = expf(v - m);
    float sum = ex;
#pragma unroll
    for (int o = 32; o > 0; o >>= 1) sum += __shfl_xor(sum, o);
    out[(size_t)node * C_DIM + c] = (v - m) - logf(sum);
}

// ---------------------------------------------------------------------------
extern "C" void kernel_launch(void* const* d_in, const int* in_sizes, int n_in,
                              void* d_out, int out_size, void* d_ws, size_t ws_size,
                              hipStream_t stream) {
    const float* x = (const float*)d_in[0];
    const int* ei  = (const int*)d_in[1];   // [2, E]
    const float* W = (const float*)d_in[2];
    const float* b = (const float*)d_in[3];
    const int* src = ei;
    const int* dst = ei + N_EDGES;
    float* out = (float*)d_out;

    char* ws = (char*)d_ws;
    size_t off = 0;
    auto alloc = [&](size_t bytes) -> void* {
        void* p = ws + off;
        off = (off + bytes + 255) & ~(size_t)255;
        return p;
    };
    int*          deg     = (int*)alloc(sizeof(int) * N_NODES);
    int*          cursor  = (int*)alloc(sizeof(int) * N_NODES);
    float*        dinv    = (float*)alloc(sizeof(float) * N_NODES);
    int*          row_ptr = (int*)alloc(sizeof(int) * (N_NODES + 1));
    int*          blksum  = (int*)alloc(sizeof(int) * 1024);
    unsigned int* pairs   = (unsigned int*)alloc(sizeof(unsigned int) * (N_EDGES + N_NODES));
    __half*       h0h     = (__half*)alloc(sizeof(__half) * (size_t)N_NODES * C_DIM);
    __half*       hA      = (__half*)alloc(sizeof(__half) * (size_t)N_NODES * C_DIM);
    __half*       hB      = (__half*)alloc(sizeof(__half) * (size_t)N_NODES * C_DIM);
    (void)ws_size;

    const int NB_N  = (N_NODES + 255) / 256;
    const int NB_E  = (N_EDGES + 255) / 256;
    const int NB_EN = (N_EDGES + N_NODES + 255) / 256;
    const int NB_NODE4 = (N_NODES + 3) / 4;

    init_deg_kernel<<<NB_N, 256, 0, stream>>>(deg, cursor);
    count_deg_kernel<<<NB_E, 256, 0, stream>>>(dst, deg);
    dinv_kernel<<<NB_N, 256, 0, stream>>>(deg, dinv);
    scan_block_kernel<<<NB_N, 256, 0, stream>>>(deg, row_ptr, blksum);
    scan_top_kernel<<<1, 512, 0, stream>>>(blksum, NB_N);
    scan_add_kernel<<<NB_N, 256, 0, stream>>>(row_ptr, blksum);
    scatter_kernel<<<NB_EN, 256, 0, stream>>>(src, dst, dinv, row_ptr, cursor, pairs);

    gemm_relu_kernel<<<(N_NODES + 127) / 128, 256, 0, stream>>>(x, W, b, h0h);

    const __half* cur = h0h;
    __half* bufs[2] = {hA, hB};
    for (int it = 0; it < K_ITERS; it++) {
        __half* nxt = bufs[it & 1];
        spmm_step_kernel<<<NCHUNK * BPC, 256, 0, stream>>>(row_ptr, pairs, cur, h0h, nxt);
        cur = nxt;
    }

    logsoftmax_kernel<<<NB_NODE4, 256, 0, stream>>>(cur, out);
}

// Round 4
// 3043.348 us; speedup vs baseline: 2.3373x; 2.3373x over previous
//
#include <hip/hip_runtime.h>
#include <hip/hip_fp16.h>
#include <math.h>

#define N_NODES 100000
#define N_EDGES 3200000
#define F_INDIM 512
#define C_DIM 64
#define K_ITERS 50
#define ALPHA_F 0.1f

// ---------------------------------------------------------------------------
// CSR build
// ---------------------------------------------------------------------------
__global__ void init_deg_kernel(int* __restrict__ deg, int* __restrict__ cursor) {
    int i = blockIdx.x * 256 + threadIdx.x;
    if (i < N_NODES) { deg[i] = 1; cursor[i] = 0; }  // 1 = self loop
}

__global__ void count_deg_kernel(const int* __restrict__ dst, int* __restrict__ deg) {
    int e = blockIdx.x * 256 + threadIdx.x;
    if (e < N_EDGES) atomicAdd(&deg[dst[e]], 1);
}

__global__ void dinv_kernel(const int* __restrict__ deg, float* __restrict__ dinv) {
    int i = blockIdx.x * 256 + threadIdx.x;
    if (i < N_NODES) dinv[i] = rsqrtf((float)deg[i]);
}

__global__ void scan_block_kernel(const int* __restrict__ deg, int* __restrict__ row_ptr,
                                  int* __restrict__ blksum) {
    __shared__ int tmp[256];
    int i = blockIdx.x * 256 + threadIdx.x;
    int v = (i < N_NODES) ? deg[i] : 0;
    tmp[threadIdx.x] = v;
    __syncthreads();
    for (int o = 1; o < 256; o <<= 1) {
        int t = (threadIdx.x >= o) ? tmp[threadIdx.x - o] : 0;
        __syncthreads();
        tmp[threadIdx.x] += t;
        __syncthreads();
    }
    if (i < N_NODES) row_ptr[i] = tmp[threadIdx.x] - v;
    if (threadIdx.x == 255) blksum[blockIdx.x] = tmp[255];
}

__global__ void scan_top_kernel(int* __restrict__ blksum, int nb) {
    __shared__ int tmp[512];
    int v = (threadIdx.x < nb) ? blksum[threadIdx.x] : 0;
    tmp[threadIdx.x] = v;
    __syncthreads();
    for (int o = 1; o < 512; o <<= 1) {
        int t = (threadIdx.x >= o) ? tmp[threadIdx.x - o] : 0;
        __syncthreads();
        tmp[threadIdx.x] += t;
        __syncthreads();
    }
    if (threadIdx.x < nb) blksum[threadIdx.x] = tmp[threadIdx.x] - v;
}

__global__ void scan_add_kernel(int* __restrict__ row_ptr, const int* __restrict__ blksum) {
    int i = blockIdx.x * 256 + threadIdx.x;
    if (i < N_NODES) row_ptr[i] += blksum[blockIdx.x];
    if (i == 0) row_ptr[N_NODES] = N_EDGES + N_NODES;
}

// packed edge: (col << 15) | (fp16 bits of val; val > 0 so sign bit is 0)
__global__ void scatter_kernel(const int* __restrict__ src, const int* __restrict__ dst,
                               const float* __restrict__ dinv, const int* __restrict__ row_ptr,
                               int* __restrict__ cursor, unsigned int* __restrict__ pairs) {
    int e = blockIdx.x * 256 + threadIdx.x;
    if (e < N_EDGES) {
        int s = src[e], d = dst[e];
        int pos = atomicAdd(&cursor[d], 1);
        unsigned short hv = __half_as_ushort(__float2half(dinv[s] * dinv[d]));
        pairs[row_ptr[d] + pos] = ((unsigned int)s << 15) | (unsigned int)(hv & 0x7FFF);
    } else if (e < N_EDGES + N_NODES) {
        int i = e - N_EDGES;
        int pos = atomicAdd(&cursor[i], 1);
        float di = dinv[i];
        unsigned short hv = __half_as_ushort(__float2half(di * di));
        pairs[row_ptr[i] + pos] = ((unsigned int)i << 15) | (unsigned int)(hv & 0x7FFF);
    }
}

// ---------------------------------------------------------------------------
// GEMM: h0 = relu(x @ W + b) -> h0h fp16 [N][64]
// 128 rows x 64 cols per block, 256 threads, 4x8 register blocking.
// ---------------------------------------------------------------------------
__global__ __launch_bounds__(256) void gemm_relu_kernel(const float* __restrict__ x,
                                                        const float* __restrict__ W,
                                                        const float* __restrict__ b,
                                                        __half* __restrict__ h0h) {
    __shared__ float xs[128][36];
    __shared__ float ws[32][64];
    const int tid = threadIdx.x;
    const int c0 = (tid & 7) * 8;
    const int r0 = (tid >> 3) * 4;
    const int row0 = blockIdx.x * 128;

    float acc[4][8];
#pragma unroll
    for (int j = 0; j < 4; j++)
#pragma unroll
        for (int i = 0; i < 8; i++) acc[j][i] = 0.f;

    for (int kc = 0; kc < 16; kc++) {
        const int k0 = kc * 32;
        __syncthreads();
#pragma unroll
        for (int p = 0; p < 4; p++) {
            int lr = p * 32 + (tid >> 3);
            int gr = row0 + lr;
            if (gr >= N_NODES) gr = N_NODES - 1;
            float4 v = *reinterpret_cast<const float4*>(
                &x[(size_t)gr * F_INDIM + k0 + (tid & 7) * 4]);
            *reinterpret_cast<float4*>(&xs[lr][(tid & 7) * 4]) = v;
        }
#pragma unroll
        for (int p = 0; p < 2; p++) {
            int fi = p * 256 + tid;
            float4 v = *reinterpret_cast<const float4*>(
                &W[(size_t)(k0 + (fi >> 4)) * C_DIM + (fi & 15) * 4]);
            *reinterpret_cast<float4*>(&ws[fi >> 4][(fi & 15) * 4]) = v;
        }
        __syncthreads();
#pragma unroll
        for (int k = 0; k < 32; k++) {
            float4 w0 = *reinterpret_cast<const float4*>(&ws[k][c0]);
            float4 w1 = *reinterpret_cast<const float4*>(&ws[k][c0 + 4]);
            float wr[8] = {w0.x, w0.y, w0.z, w0.w, w1.x, w1.y, w1.z, w1.w};
#pragma unroll
            for (int j = 0; j < 4; j++) {
                float xv = xs[r0 + j][k];
#pragma unroll
                for (int i = 0; i < 8; i++) acc[j][i] = fmaf(xv, wr[i], acc[j][i]);
            }
        }
    }

    const float4 b0 = *reinterpret_cast<const float4*>(&b[c0]);
    const float4 b1 = *reinterpret_cast<const float4*>(&b[c0 + 4]);
    float bb[8] = {b0.x, b0.y, b0.z, b0.w, b1.x, b1.y, b1.z, b1.w};
#pragma unroll
    for (int j = 0; j < 4; j++) {
        int gr = row0 + r0 + j;
        if (gr < N_NODES) {
            float o[8];
#pragma unroll
            for (int i = 0; i < 8; i++) {
                float v = acc[j][i] + bb[i];
                o[i] = v > 0.f ? v : 0.f;
            }
            union { float4 f; __half2 h[4]; } hw;
            hw.h[0] = __floats2half2_rn(o[0], o[1]);
            hw.h[1] = __floats2half2_rn(o[2], o[3]);
            hw.h[2] = __floats2half2_rn(o[4], o[5]);
            hw.h[3] = __floats2half2_rn(o[6], o[7]);
            *reinterpret_cast<float4*>(h0h + (size_t)gr * C_DIM + c0) = hw.f;
        }
    }
}

// ---------------------------------------------------------------------------
// Propagation step: hn = 0.9 * (A_hat @ hp) + 0.1 * x0   (all fp16 storage)
// One wave per node. lane = (esub 0..7, cgrp 0..7): cgrp picks 16B of the
// 128B row, esub picks the edge. 4 slots -> 32 edges (4KB) in flight.
// Last step fuses log-softmax and writes fp32 out.
// ---------------------------------------------------------------------------
__device__ __forceinline__ void acc_fma8(float acc[8], float v, float4 g) {
    union { float f; __half2 h; } u;
    u.f = g.x; float2 f0 = __half22float2(u.h);
    acc[0] = fmaf(v, f0.x, acc[0]); acc[1] = fmaf(v, f0.y, acc[1]);
    u.f = g.y; float2 f1 = __half22float2(u.h);
    acc[2] = fmaf(v, f1.x, acc[2]); acc[3] = fmaf(v, f1.y, acc[3]);
    u.f = g.z; float2 f2 = __half22float2(u.h);
    acc[4] = fmaf(v, f2.x, acc[4]); acc[5] = fmaf(v, f2.y, acc[5]);
    u.f = g.w; float2 f3 = __half22float2(u.h);
    acc[6] = fmaf(v, f3.x, acc[6]); acc[7] = fmaf(v, f3.y, acc[7]);
}

__device__ __forceinline__ void spmm_body(const int* __restrict__ rp,
                                          const unsigned int* __restrict__ pairs,
                                          const __half* __restrict__ hp,
                                          const __half* __restrict__ x0,
                                          __half* __restrict__ hn,
                                          float* __restrict__ out,
                                          const bool last) {
    const int node = blockIdx.x * 4 + (threadIdx.x >> 6);
    if (node >= N_NODES) return;
    const int lane = threadIdx.x & 63;
    const int esub = lane >> 3;        // 0..7
    const int cbase = (lane & 7) * 8;  // 8 fp16 channels per lane

    // final channel this lane owns after the halving reduction (lane bits only)
    int cb = cbase + ((esub & 1) ? 4 : 0) + ((esub & 2) ? 2 : 0) + ((esub & 4) ? 1 : 0);
    const size_t oidx = (size_t)node * C_DIM + cb;
    // issue x0 load early (independent of the gather chain)
    unsigned short xbits =
        __builtin_nontemporal_load((const unsigned short*)(x0 + oidx));

    const int s = rp[node];
    const int e = rp[node + 1];

    float acc[8] = {0.f, 0.f, 0.f, 0.f, 0.f, 0.f, 0.f, 0.f};

    const int j0 = s + esub;
    unsigned int p0 = 0, p1 = 0, p2 = 0, p3 = 0;  // col 0 / +0.0 when inactive
    if (j0 < e)      p0 = __builtin_nontemporal_load(pairs + j0);
    if (j0 + 8 < e)  p1 = __builtin_nontemporal_load(pairs + j0 + 8);
    if (j0 + 16 < e) p2 = __builtin_nontemporal_load(pairs + j0 + 16);
    if (j0 + 24 < e) p3 = __builtin_nontemporal_load(pairs + j0 + 24);

    for (int t = s; t < e; t += 32) {
        const int jn = t + 32 + esub;
        unsigned int n0 = 0, n1 = 0, n2 = 0, n3 = 0;
        if (jn < e)      n0 = __builtin_nontemporal_load(pairs + jn);
        if (jn + 8 < e)  n1 = __builtin_nontemporal_load(pairs + jn + 8);
        if (jn + 16 < e) n2 = __builtin_nontemporal_load(pairs + jn + 16);
        if (jn + 24 < e) n3 = __builtin_nontemporal_load(pairs + jn + 24);

        float4 g0 = *reinterpret_cast<const float4*>(hp + (size_t)(p0 >> 15) * C_DIM + cbase);
        float4 g1 = *reinterpret_cast<const float4*>(hp + (size_t)(p1 >> 15) * C_DIM + cbase);
        float4 g2 = *reinterpret_cast<const float4*>(hp + (size_t)(p2 >> 15) * C_DIM + cbase);
        float4 g3 = *reinterpret_cast<const float4*>(hp + (size_t)(p3 >> 15) * C_DIM + cbase);

        acc_fma8(acc, __half2float(__ushort_as_half((unsigned short)(p0 & 0x7FFFu))), g0);
        acc_fma8(acc, __half2float(__ushort_as_half((unsigned short)(p1 & 0x7FFFu))), g1);
        acc_fma8(acc, __half2float(__ushort_as_half((unsigned short)(p2 & 0x7FFFu))), g2);
        acc_fma8(acc, __half2float(__ushort_as_half((unsigned short)(p3 & 0x7FFFu))), g3);

        p0 = n0; p1 = n1; p2 = n2; p3 = n3;
    }

    // halving butterfly over esub bits (lane bits 3,4,5): 8 accs -> 1
    {
        const bool hi = (esub & 1);
#pragma unroll
        for (int i = 0; i < 4; i++) {
            float send = hi ? acc[i] : acc[i + 4];
            float keep = hi ? acc[i + 4] : acc[i];
            acc[i] = keep + __shfl_xor(send, 8);
        }
    }
    {
        const bool hi = (esub & 2);
#pragma unroll
        for (int i = 0; i < 2; i++) {
            float send = hi ? acc[i] : acc[i + 2];
            float keep = hi ? acc[i + 2] : acc[i];
            acc[i] = keep + __shfl_xor(send, 16);
        }
    }
    {
        const bool hi = (esub & 4);
        float send = hi ? acc[0] : acc[1];
        float keep = hi ? acc[1] : acc[0];
        acc[0] = keep + __shfl_xor(send, 32);
    }

    float xv = __half2float(__ushort_as_half(xbits));
    float o = (1.0f - ALPHA_F) * acc[0] + ALPHA_F * xv;

    if (!last) {
        hn[oidx] = __float2half(o);
    } else {
        float m = o;
#pragma unroll
        for (int of = 32; of > 0; of >>= 1) m = fmaxf(m, __shfl_xor(m, of));
        float ex = expf(o - m);
        float sum = ex;
#pragma unroll
        for (int of = 32; of > 0; of >>= 1) sum += __shfl_xor(sum, of);
        out[oidx] = (o - m) - logf(sum);
    }
}

__global__ __launch_bounds__(256) void spmm_mid_kernel(const int* __restrict__ rp,
                                                       const unsigned int* __restrict__ pairs,
                                                       const __half* __restrict__ hp,
                                                       const __half* __restrict__ x0,
                                                       __half* __restrict__ hn) {
    spmm_body(rp, pairs, hp, x0, hn, nullptr, false);
}

__global__ __launch_bounds__(256) void spmm_last_kernel(const int* __restrict__ rp,
                                                        const unsigned int* __restrict__ pairs,
                                                        const __half* __restrict__ hp,
                                                        const __half* __restrict__ x0,
                                                        float* __restrict__ out) {
    spmm_body(rp, pairs, hp, x0, nullptr, out, true);
}

// ---------------------------------------------------------------------------
extern "C" void kernel_launch(void* const* d_in, const int* in_sizes, int n_in,
                              void* d_out, int out_size, void* d_ws, size_t ws_size,
                              hipStream_t stream) {
    const float* x = (const float*)d_in[0];
    const int* ei  = (const int*)d_in[1];   // [2, E]
    const float* W = (const float*)d_in[2];
    const float* b = (const float*)d_in[3];
    const int* src = ei;
    const int* dst = ei + N_EDGES;
    float* out = (float*)d_out;

    char* ws = (char*)d_ws;
    size_t off = 0;
    auto alloc = [&](size_t bytes) -> void* {
        void* p = ws + off;
        off = (off + bytes + 255) & ~(size_t)255;
        return p;
    };
    int*          deg     = (int*)alloc(sizeof(int) * N_NODES);
    int*          cursor  = (int*)alloc(sizeof(int) * N_NODES);
    float*        dinv    = (float*)alloc(sizeof(float) * N_NODES);
    int*          row_ptr = (int*)alloc(sizeof(int) * (N_NODES + 1));
    int*          blksum  = (int*)alloc(sizeof(int) * 1024);
    unsigned int* pairs   = (unsigned int*)alloc(sizeof(unsigned int) * (N_EDGES + N_NODES));
    __half*       h0h     = (__half*)alloc(sizeof(__half) * (size_t)N_NODES * C_DIM);
    __half*       hA      = (__half*)alloc(sizeof(__half) * (size_t)N_NODES * C_DIM);
    __half*       hB      = (__half*)alloc(sizeof(__half) * (size_t)N_NODES * C_DIM);
    (void)ws_size;

    const int NB_N  = (N_NODES + 255) / 256;
    const int NB_E  = (N_EDGES + 255) / 256;
    const int NB_EN = (N_EDGES + N_NODES + 255) / 256;
    const int NB_NODE4 = (N_NODES + 3) / 4;

    init_deg_kernel<<<NB_N, 256, 0, stream>>>(deg, cursor);
    count_deg_kernel<<<NB_E, 256, 0, stream>>>(dst, deg);
    dinv_kernel<<<NB_N, 256, 0, stream>>>(deg, dinv);
    scan_block_kernel<<<NB_N, 256, 0, stream>>>(deg, row_ptr, blksum);
    scan_top_kernel<<<1, 512, 0, stream>>>(blksum, NB_N);
    scan_add_kernel<<<NB_N, 256, 0, stream>>>(row_ptr, blksum);
    scatter_kernel<<<NB_EN, 256, 0, stream>>>(src, dst, dinv, row_ptr, cursor, pairs);

    gemm_relu_kernel<<<(N_NODES + 127) / 128, 256, 0, stream>>>(x, W, b, h0h);

    const __half* cur = h0h;
    __half* bufs[2] = {hA, hB};
    for (int it = 0; it < K_ITERS - 1; it++) {
        __half* nxt = bufs[it & 1];
        spmm_mid_kernel<<<NB_NODE4, 256, 0, stream>>>(row_ptr, pairs, cur, h0h, nxt);
        cur = nxt;
    }
    spmm_last_kernel<<<NB_NODE4, 256, 0, stream>>>(row_ptr, pairs, cur, h0h, out);
}